// Round 9
// baseline (40.115 us; speedup 1.0000x reference)
//
#include <hip/hip_runtime.h>

#define B_SZ   512
#define IN_F   256
#define OUT_F  256
#define NINT   15
#define IHALF  128            // input features per block (IN-dim split in 2)
#define NC4    (IHALF * NINT) // float4 coeff entries per block = 1920

typedef const __attribute__((address_space(1))) void gvoid_t;
typedef __attribute__((address_space(3))) void lvoid_t;

// One-time x transpose: xq[i4][b] = x[b][4*i4 .. 4*i4+3]  (i4 in [0,64), b in [0,512))
// Makes the main kernel's per-eval x read lane-consecutive (coalesced).
__global__ void xq_kernel(const float* __restrict__ x, float4* __restrict__ xq) {
    int T  = blockIdx.x * 256 + threadIdx.x;  // 32768 float4s total
    int b  = T >> 6;                          // row
    int i4 = T & 63;                          // quad within row
    float4 v = reinterpret_cast<const float4*>(x)[T];  // coalesced read (T = b*64+i4)
    xq[i4 * 512 + b] = v;                     // scattered write (once, tiny)
}

__device__ __forceinline__ float kan_eval(float wv, float xv,
                                          const float4* __restrict__ sc, int cbase) {
    const float kD = 2.0f / 15.0f;                 // fl32(2/15), XLA's delta bits
    float wx = wv * xv;                            // ref's exact f32 product
    float xc = fminf(fmaxf(wx, -1.0f), 1.0f);
    float u  = __builtin_fmaf(xc, 7.5f, 7.4999f);  // down-biased floor guess
    int   i0 = (int)u;                             // ∈ [0,14]
    float f0 = (float)i0;
    float blo = __fadd_rn(__fmul_rn(f0, kD), -1.0f);                   // bp[i0]
    float bhi = __fadd_rn(__fmul_rn(__fadd_rn(f0, 1.0f), kD), -1.0f);  // bp[i0+1]
    bool  up = (xc >= bhi);                        // exact searchsorted(right)-1
    int   j  = i0 + (up ? 1 : 0);                  // j<=14 automatic: bp[15] > 1 >= xc
    float bj = up ? bhi : blo;
    float dx = xc - bj;                            // ref's exact f32 sub
    float4 c = sc[cbase + j];
    return __builtin_fmaf(__builtin_fmaf(__builtin_fmaf(c.w, dx, c.z), dx, c.y), dx, c.x);
}

__global__ __launch_bounds__(512, 4)
void kan_kernel(const float4* __restrict__ xq,
                const float* __restrict__ w,
                const float* __restrict__ bias,
                const float* __restrict__ coeffs,
                float* __restrict__ out)
{
    __shared__ float4 sc[NC4];        // 30720 B -> 2 blocks/CU
    __shared__ float4 sw4[IHALF / 4]; // 512 B: weights half-row

    const int o = blockIdx.x >> 1;    // output feature
    const int h = blockIdx.x & 1;     // which IN-half
    const int b = threadIdx.x;        // batch row

    // Stage this half's coeffs (30720 B) global->LDS, width-16, linear dest.
    const float4* gsrc = reinterpret_cast<const float4*>(coeffs)
                         + ((size_t)o * IN_F + h * IHALF) * NINT;
    #pragma unroll
    for (int k = 0; k < 4; ++k) {
        int t = b + k * 512;
        if (t < NC4) {  // k==3: b<384 = 6 whole waves — wave-uniform predicate
            __builtin_amdgcn_global_load_lds((gvoid_t*)(gsrc + t), (lvoid_t*)(sc + t), 16, 0, 0);
        }
    }
    if (b < IHALF / 4) {
        sw4[b] = reinterpret_cast<const float4*>(w + (size_t)o * IN_F + h * IHALF)[b];
    }
    __syncthreads();

    float a0 = 0.f, a1 = 0.f, a2 = 0.f, a3 = 0.f;

    #pragma unroll 4
    for (int i4 = 0; i4 < IHALF / 4; ++i4) {
        // coalesced: lanes (=b) read consecutive 16B from the transposed layout
        float4 xv = xq[(h * 32 + i4) * 512 + b];
        float4 wv = sw4[i4];
        int cb = i4 * 4 * NINT;
        a0 += kan_eval(wv.x, xv.x, sc, cb);
        a1 += kan_eval(wv.y, xv.y, sc, cb + NINT);
        a2 += kan_eval(wv.z, xv.z, sc, cb + 2 * NINT);
        a3 += kan_eval(wv.w, xv.w, sc, cb + 3 * NINT);
    }

    float acc = (a0 + a1) + (a2 + a3);
    if (h == 0) acc += bias[o];
    // out zeroed by memsetAsync each launch; exactly 2 commutative adds from
    // exact 0 per element -> bitwise deterministic regardless of arrival order.
    atomicAdd(out + (size_t)b * OUT_F + o, acc);
}

extern "C" void kernel_launch(void* const* d_in, const int* in_sizes, int n_in,
                              void* d_out, int out_size, void* d_ws, size_t ws_size,
                              hipStream_t stream) {
    (void)ws_size;

    const float *x = nullptr, *wgt = nullptr, *bias = nullptr, *coeffs = nullptr;
    for (int i = 0; i < n_in; ++i) {
        switch (in_sizes[i]) {
            case 512 * 256:           x      = (const float*)d_in[i]; break;
            case 256 * 256:           wgt    = (const float*)d_in[i]; break;
            case 256:                 bias   = (const float*)d_in[i]; break;
            case 256 * 256 * 15 * 4:  coeffs = (const float*)d_in[i]; break;
            default: break;
        }
    }

    float4* xq = (float4*)d_ws;  // 512 KB scratch: transposed x

    hipMemsetAsync(d_out, 0, (size_t)out_size * sizeof(float), stream);
    xq_kernel<<<128, 256, 0, stream>>>(x, xq);
    kan_kernel<<<2 * OUT_F, B_SZ, 0, stream>>>(xq, wgt, bias, coeffs, (float*)d_out);
}